// Round 4
// baseline (624.699 us; speedup 1.0000x reference)
//
#include <hip/hip_runtime.h>
#include <cstdint>

#define N_NODES 172032
#define BATCH   8192
#define NPS     21
#define F_IN    171
#define K1P     192      // K padded to multiple of 32 for layer-1 GEMM
#define F_HID   256
#define F_OUT   128
#define SX_F    (NPS * F_IN)   // 3591 floats per sample in x/out_x
#define SPB     3              // samples per fused block
#define NBLK    2731           // ceil(8192/3)

typedef unsigned short u16;
typedef __attribute__((ext_vector_type(8))) short  bf16x8;
typedef __attribute__((ext_vector_type(4))) float  f32x4;
typedef __attribute__((ext_vector_type(4))) u16    u16x4;

__device__ inline u16 f2bf(float f) {
    unsigned u = __float_as_uint(f);
    unsigned r = u + 0x7FFFu + ((u >> 16) & 1u);
    return (u16)(r >> 16);
}
__device__ inline float bf2f(u16 h) { return __uint_as_float(((unsigned)h) << 16); }
__device__ inline float lrelu(float v) { return v > 0.f ? v : 0.2f * v; }

// ---- static edge structure (local node ids within a 21-node sample) ----
// node 0 = query, 1..10 = docs, 11..20 = titles
__device__ inline int deg_of(int n)  { return n == 0 ? 11 : (n <= 10 ? 3 : 2); }
__device__ inline int edge_base(int n) { return n == 0 ? 0 : (n <= 10 ? 11 + 3*(n-1) : 41 + 2*(n-11)); }
__device__ inline int src_of(int n, int k) {
    if (n == 0)  return k < 10 ? k + 1 : 0;
    if (n <= 10) return k == 0 ? 0 : (k == 1 ? n + 10 : n);
    return k == 0 ? n - 10 : n;
}

__device__ inline float wave_red(float v) {
    for (int off = 32; off; off >>= 1) v += __shfl_down(v, off);
    return v;
}

// ------------------------------------------------------------------
// prep_w: W1 (256x171 f32) -> W1b (256x192 bf16, zero K-pad)
//         W2 (128x256 f32) -> W2b (128x256 bf16)
// ------------------------------------------------------------------
__global__ __launch_bounds__(256) void prep_w(const float* __restrict__ W1, const float* __restrict__ W2,
                                              u16* __restrict__ W1b, u16* __restrict__ W2b)
{
    int id = blockIdx.x * 256 + threadIdx.x;
    if (id < 256 * K1P) {
        int r = id / K1P, k = id - r * K1P;
        W1b[id] = (k < F_IN) ? f2bf(W1[r * F_IN + k]) : (u16)0;
    }
    if (id < 128 * 256) W2b[id] = f2bf(W2[id]);
}

// ------------------------------------------------------------------
// mega: one block = 3 samples (63 rows -> 64-row GEMM tiles).
// Phase 1: gather tables / x -> out_x (fp32) + A1-tile (bf16, LDS)
// Phase 2: GEMM1 (64x192 @ W1b^T -> 64x256), B per-fragment from L2
// Phase 3: h1 -> LDS + in-register attention logits
// Phase 4: softmax1    Phase 5: agg1 -> y (bf16, overwrites A1 region)
// Phase 6: GEMM2 (64x256 @ W2b^T -> 64x128)
// Phase 7: h2 -> LDS (overwrites h1) + logits2
// Phase 8: softmax2    Phase 9: agg2 -> out_hid + readout -> out_y
// LDS ~68 KB -> 2 blocks/CU. No intermediate HBM traffic at all.
// ------------------------------------------------------------------
__global__ __launch_bounds__(256, 2) void mega(const int* __restrict__ iptr, const float* __restrict__ x,
                        const int* __restrict__ click, const int* __restrict__ query,
                        const int* __restrict__ docu, const int* __restrict__ title_id,
                        const float* __restrict__ qtab, const float* __restrict__ dtab,
                        const float* __restrict__ ttab, const float* __restrict__ ptab,
                        const float* __restrict__ ctab,
                        const u16* __restrict__ W1b, const u16* __restrict__ W2b,
                        const float* __restrict__ as1, const float* __restrict__ ad1,
                        const float* __restrict__ b1,
                        const float* __restrict__ as2, const float* __restrict__ ad2,
                        const float* __restrict__ b2,
                        const float* __restrict__ Wl, const float* __restrict__ bl,
                        float* __restrict__ out_x, float* __restrict__ out_hid,
                        float* __restrict__ out_y)
{
    constexpr int SA1 = 200;   // A1 row stride (u16), 400 B
    constexpr int SA2 = 264;   // Y  row stride (u16), 528 B
    __shared__ __align__(16) u16 R2[64 * SA2];   // A1 then Y       (33.8 KB)
    __shared__ __align__(16) u16 R1[64 * F_HID]; // h1 then h2      (32 KB)
    __shared__ float s_part[2][64], d_part[2][64];
    __shared__ float alpha[SPB * 61];
    __shared__ float rpart[SPB * NPS][2];
    __shared__ int   dz[SPB][10], tz[SPB][10], sq[SPB];
    __shared__ float sclk[SPB];

    const int blk = blockIdx.x, tid = threadIdx.x;
    const int s0  = blk * SPB;
    const int nsamp = (s0 + SPB <= BATCH) ? SPB : (BATCH - s0);
    const int nrow  = nsamp * NPS;
    const int i     = iptr[0];

    const int lane = tid & 63, w = tid >> 6;
    const int wr = w >> 1, wc = w & 1;
    const int lm = lane & 15, lq = lane >> 4;

    // ---- phase 0: per-sample scalars ----
    if (tid < 30)      { int ss = tid / 10, j = tid - ss*10;       if (ss < nsamp) dz[ss][j] = docu[(s0+ss)*10 + j]; }
    else if (tid < 60) { int t = tid - 30; int ss = t/10, j = t - ss*10; if (ss < nsamp) tz[ss][j] = title_id[(s0+ss)*10 + j]; }
    else if (tid >= 64 && tid < 67) { int ss = tid - 64; if (ss < nsamp) sq[ss]   = query[s0+ss]; }
    else if (tid >= 67 && tid < 70) { int ss = tid - 67; if (ss < nsamp) sclk[ss] = ctab[click[s0+ss]]; }
    __syncthreads();

    // ---- phase 1: build A1 (bf16 LDS) + write out_x (fp32) ----
    u16* A1 = R2;
    if (i == 0) {
        // cols 0..159 from tables (rows 640 B, float4-aligned)
        for (int id = tid; id < nrow * 40; id += 256) {
            int r = id / 40, c4 = (id - r*40) * 4;
            int ss = r / NPS, p = r - ss*NPS;
            const float* srcp;
            if (p == 0)       srcp = qtab + (long)sq[ss] * 160;
            else if (p <= 10) srcp = dtab + (long)dz[ss][p-1] * 160;
            else              srcp = ttab + (long)tz[ss][p-11] * 160;
            float4 v = *(const float4*)(srcp + c4);
            float* ox = out_x + (long)(s0+ss) * SX_F + p * F_IN + c4;
            ox[0] = v.x; ox[1] = v.y; ox[2] = v.z; ox[3] = v.w;
            u16x4 hv = { f2bf(v.x), f2bf(v.y), f2bf(v.z), f2bf(v.w) };
            *(u16x4*)(A1 + r * SA1 + c4) = hv;
        }
        // cols 160..170: specials + x tail
        for (int id = tid; id < nrow * 11; id += 256) {
            int r = id / 11, c = 160 + (id - r*11);
            int ss = r / NPS, p = r - ss*NPS;
            float v;
            if (p >= 1 && p <= 10 && c == 160)      v = ptab[p-1];
            else if (p >= 1 && p <= 10 && c == 161) v = sclk[ss];
            else v = x[(long)(s0+ss) * SX_F + p * F_IN + c];
            out_x[(long)(s0+ss) * SX_F + p * F_IN + c] = v;
            A1[r * SA1 + c] = f2bf(v);
        }
    } else {
        const long base0 = (long)s0 * SX_F;
        for (int idx = tid; idx < nrow * F_IN; idx += 256) {
            int r = idx / F_IN, c = idx - r * F_IN;
            int ss = r / NPS, p = r - ss*NPS;
            float v = x[base0 + idx];
            if (p >= 1 && p <= 10 && c == 161 + i) v = sclk[ss];
            out_x[base0 + idx] = v;
            A1[r * SA1 + c] = f2bf(v);
        }
    }
    // zero K-pad cols 171..191 (data rows) + full pad rows
    for (int id = tid; id < nrow * 21; id += 256) {
        int r = id / 21, c = F_IN + (id - r*21);
        A1[r * SA1 + c] = 0;
    }
    for (int id = tid; id < (64 - nrow) * 24; id += 256) {
        int r = nrow + id / 24, ch = id - (id/24)*24;
        *(uint4*)(A1 + r * SA1 + ch * 8) = make_uint4(0u,0u,0u,0u);
    }
    __syncthreads();

    // ---- phase 2: GEMM1 ----
    f32x4 acc[2][8];
    #pragma unroll
    for (int f = 0; f < 2; ++f)
        #pragma unroll
        for (int g = 0; g < 8; ++g)
            acc[f][g] = (f32x4){0.f, 0.f, 0.f, 0.f};

    #pragma unroll
    for (int kb = 0; kb < K1P / 32; ++kb) {
        int koff = kb * 32 + lq * 8;
        bf16x8 a0 = *(const bf16x8*)(A1 + (wr*32 +  0 + lm) * SA1 + koff);
        bf16x8 a1 = *(const bf16x8*)(A1 + (wr*32 + 16 + lm) * SA1 + koff);
        #pragma unroll
        for (int g = 0; g < 8; ++g) {
            bf16x8 b = *(const bf16x8*)(W1b + (wc*128 + g*16 + lm) * K1P + koff);
            acc[0][g] = __builtin_amdgcn_mfma_f32_16x16x32_bf16(a0, b, acc[0][g], 0, 0, 0);
            acc[1][g] = __builtin_amdgcn_mfma_f32_16x16x32_bf16(a1, b, acc[1][g], 0, 0, 0);
        }
    }

    // ---- phase 3: h1 -> R1 + in-register logits (no barrier needed: R1 fresh) ----
    u16* h1 = R1;             // 64 x 256 bf16
    {
        float av[8], dv[8];
        #pragma unroll
        for (int g = 0; g < 8; ++g) {
            av[g] = as1[wc*128 + g*16 + lm];
            dv[g] = ad1[wc*128 + g*16 + lm];
        }
        #pragma unroll
        for (int f = 0; f < 2; ++f)
            #pragma unroll
            for (int r = 0; r < 4; ++r) {
                int row = wr*32 + f*16 + lq*4 + r;
                float sp = 0.f, dp = 0.f;
                #pragma unroll
                for (int g = 0; g < 8; ++g) {
                    float v = acc[f][g][r];
                    h1[row * F_HID + wc*128 + g*16 + lm] = f2bf(v);
                    sp += v * av[g];
                    dp += v * dv[g];
                }
                #pragma unroll
                for (int off = 1; off < 16; off <<= 1) {
                    sp += __shfl_xor(sp, off);
                    dp += __shfl_xor(dp, off);
                }
                if (lm == 0) { s_part[wc][row] = sp; d_part[wc][row] = dp; }
            }
    }
    __syncthreads();

    // ---- phase 4: softmax1 ----
    if (tid < nrow) {
        int s = tid / NPS, p = tid - s * NPS;
        int deg = deg_of(p), eb = edge_base(p);
        int sb = s * NPS;
        float dn = d_part[0][tid] + d_part[1][tid];
        float e[11];
        float m = -1e30f;
        for (int k = 0; k < deg; ++k) {
            int sn = sb + src_of(p, k);
            e[k] = lrelu(s_part[0][sn] + s_part[1][sn] + dn);
            m = fmaxf(m, e[k]);
        }
        float den = 0.f;
        for (int k = 0; k < deg; ++k) { e[k] = expf(e[k] - m); den += e[k]; }
        float inv = 1.f / den;
        for (int k = 0; k < deg; ++k) alpha[s*61 + eb + k] = e[k] * inv;
    }
    __syncthreads();

    // ---- phase 5: agg1 + relu -> Y (bf16, overwrites A1 region) ----
    u16* Y = R2;              // 64 rows x 256 cols, stride SA2
    {
        const int c = tid;    // 256 threads = F_HID
        float bc = b1[c];
        for (int s = 0; s < nsamp; ++s) {
            const u16* hs = h1 + s * NPS * F_HID;
            const float* al = alpha + s * 61;
            u16* yrow = Y + (s * NPS) * SA2;
            {
                float a = al[10] * bf2f(hs[c]);
                #pragma unroll
                for (int j = 1; j <= 10; ++j) a += al[j-1] * bf2f(hs[j * F_HID + c]);
                yrow[c] = f2bf(fmaxf(a + bc, 0.f));
            }
            #pragma unroll
            for (int j = 1; j <= 10; ++j) {
                int eb = 11 + 3*(j-1);
                float a = al[eb]   * bf2f(hs[c])
                        + al[eb+1] * bf2f(hs[(j+10) * F_HID + c])
                        + al[eb+2] * bf2f(hs[j * F_HID + c]);
                yrow[j * SA2 + c] = f2bf(fmaxf(a + bc, 0.f));
            }
            #pragma unroll
            for (int j = 1; j <= 10; ++j) {
                int eb = 41 + 2*(j-1);
                float a = al[eb]   * bf2f(hs[j * F_HID + c])
                        + al[eb+1] * bf2f(hs[(10+j) * F_HID + c]);
                yrow[(10+j) * SA2 + c] = f2bf(fmaxf(a + bc, 0.f));
            }
        }
    }
    __syncthreads();

    // ---- phase 6: GEMM2 (A = Y in LDS, rows >= nrow are garbage but only
    //      affect h2 rows >= nrow, which are never read) ----
    f32x4 acc2[2][4];
    #pragma unroll
    for (int f = 0; f < 2; ++f)
        #pragma unroll
        for (int g = 0; g < 4; ++g)
            acc2[f][g] = (f32x4){0.f, 0.f, 0.f, 0.f};

    #pragma unroll
    for (int kb = 0; kb < F_HID / 32; ++kb) {
        int koff = kb * 32 + lq * 8;
        bf16x8 a0 = *(const bf16x8*)(Y + (wr*32 +  0 + lm) * SA2 + koff);
        bf16x8 a1 = *(const bf16x8*)(Y + (wr*32 + 16 + lm) * SA2 + koff);
        #pragma unroll
        for (int g = 0; g < 4; ++g) {
            bf16x8 b = *(const bf16x8*)(W2b + (wc*64 + g*16 + lm) * F_HID + koff);
            acc2[0][g] = __builtin_amdgcn_mfma_f32_16x16x32_bf16(a0, b, acc2[0][g], 0, 0, 0);
            acc2[1][g] = __builtin_amdgcn_mfma_f32_16x16x32_bf16(a1, b, acc2[1][g], 0, 0, 0);
        }
    }

    // ---- phase 7: h2 -> R1 (h1 dead) + logits2 ----
    u16* h2 = R1;             // 64 x 128 bf16
    {
        float av[4], dv[4];
        #pragma unroll
        for (int g = 0; g < 4; ++g) {
            av[g] = as2[wc*64 + g*16 + lm];
            dv[g] = ad2[wc*64 + g*16 + lm];
        }
        #pragma unroll
        for (int f = 0; f < 2; ++f)
            #pragma unroll
            for (int r = 0; r < 4; ++r) {
                int row = wr*32 + f*16 + lq*4 + r;
                float sp = 0.f, dp = 0.f;
                #pragma unroll
                for (int g = 0; g < 4; ++g) {
                    float v = acc2[f][g][r];
                    h2[row * F_OUT + wc*64 + g*16 + lm] = f2bf(v);
                    sp += v * av[g];
                    dp += v * dv[g];
                }
                #pragma unroll
                for (int off = 1; off < 16; off <<= 1) {
                    sp += __shfl_xor(sp, off);
                    dp += __shfl_xor(dp, off);
                }
                if (lm == 0) { s_part[wc][row] = sp; d_part[wc][row] = dp; }
            }
    }
    __syncthreads();

    // ---- phase 8: softmax2 ----
    if (tid < nrow) {
        int s = tid / NPS, p = tid - s * NPS;
        int deg = deg_of(p), eb = edge_base(p);
        int sb = s * NPS;
        float dn = d_part[0][tid] + d_part[1][tid];
        float e[11];
        float m = -1e30f;
        for (int k = 0; k < deg; ++k) {
            int sn = sb + src_of(p, k);
            e[k] = lrelu(s_part[0][sn] + s_part[1][sn] + dn);
            m = fmaxf(m, e[k]);
        }
        float den = 0.f;
        for (int k = 0; k < deg; ++k) { e[k] = expf(e[k] - m); den += e[k]; }
        float inv = 1.f / den;
        for (int k = 0; k < deg; ++k) alpha[s*61 + eb + k] = e[k] * inv;
    }
    __syncthreads();

    // ---- phase 9: agg2 -> out_hid + readout partials ----
    {
        const int c    = tid & 127;
        const int half = tid >> 7;     // wave-uniform (waves 0-1 vs 2-3)
        float bc = b2[c];
        float wl = Wl[c];
        for (int s = 0; s < nsamp; ++s) {
            const u16* hs = h2 + s * NPS * F_OUT;
            const float* al = alpha + s * 61;
            long gb = (long)(s0 + s) * NPS * F_OUT;
            for (int p = half; p < NPS; p += 2) {
                int deg = deg_of(p), eb = edge_base(p);
                float a = 0.f;
                for (int k = 0; k < deg; ++k) a += al[eb + k] * bf2f(hs[src_of(p,k) * F_OUT + c]);
                float hv = a + bc;
                out_hid[gb + p * F_OUT + c] = hv;
                float rv = wave_red(fmaxf(hv, 0.f) * wl);
                if (lane == 0) rpart[s * NPS + p][w & 1] = rv;
            }
        }
    }
    __syncthreads();

    // ---- readout: y = sigmoid(sum_c relu(hid)*Wl + bl) ----
    if (tid < nrow) {
        float v = rpart[tid][0] + rpart[tid][1] + bl[0];
        out_y[(long)s0 * NPS + tid] = 1.f / (1.f + expf(-v));
    }
}

// ------------------------------------------------------------------
extern "C" void kernel_launch(void* const* d_in, const int* in_sizes, int n_in,
                              void* d_out, int out_size, void* d_ws, size_t ws_size,
                              hipStream_t stream) {
    const int*   ip    = (const int*)  d_in[0];
    const float* x     = (const float*)d_in[1];
    const int*   click = (const int*)  d_in[4];
    const int*   query = (const int*)  d_in[5];
    const int*   docu  = (const int*)  d_in[6];
    const int*   title = (const int*)  d_in[7];
    const float* qtab  = (const float*)d_in[8];
    const float* dtab  = (const float*)d_in[9];
    const float* ttab  = (const float*)d_in[10];
    const float* ptab  = (const float*)d_in[11];
    const float* ctab  = (const float*)d_in[12];
    const float* W1    = (const float*)d_in[13];
    const float* as1   = (const float*)d_in[14];
    const float* ad1   = (const float*)d_in[15];
    const float* b1    = (const float*)d_in[16];
    const float* W2    = (const float*)d_in[17];
    const float* as2   = (const float*)d_in[18];
    const float* ad2   = (const float*)d_in[19];
    const float* b2    = (const float*)d_in[20];
    const float* Wl    = (const float*)d_in[21];
    const float* bl    = (const float*)d_in[22];

    float* out_hid = (float*)d_out;
    float* out_y   = out_hid + (long)N_NODES * F_OUT;
    float* out_x   = out_y + N_NODES;

    u16* W1b = (u16*)d_ws;                 // 256*192 = 49,152 u16
    u16* W2b = W1b + 256 * K1P;            // 128*256 = 32,768 u16

    prep_w<<<192, 256, 0, stream>>>(W1, W2, W1b, W2b);
    mega<<<NBLK, 256, 0, stream>>>(ip, x, click, query, docu, title,
                                   qtab, dtab, ttab, ptab, ctab,
                                   W1b, W2b, as1, ad1, b1, as2, ad2, b2,
                                   Wl, bl, out_x, out_hid, out_y);
}